// Round 3
// baseline (2372.411 us; speedup 1.0000x reference)
//
#include <hip/hip_runtime.h>
#include <hip/hip_cooperative_groups.h>
#include <hip/hip_bf16.h>

namespace cg = cooperative_groups;

#define FDIM 256
#define CHUNK 64
#define T_STEPS 8
#define LR_X 0.1f
#define GRID_PERSIST 1024   // 4 blocks/CU x 256 CU, guaranteed co-resident via launch_bounds(256,4)

// ---- CSR build ------------------------------------------------------------

__global__ void k_count(const int* __restrict__ dst, int* __restrict__ cnt, int E) {
    int e = blockIdx.x * blockDim.x + threadIdx.x;
    if (e < E) atomicAdd(&cnt[dst[e]], 1);
}

// Exclusive scan of counts (in cntcur) -> start[0..n] and cursor back into cntcur.
__global__ __launch_bounds__(1024) void k_scan(int* cntcur, int* start, int n) {
    __shared__ int sdata[1024];
    int running = 0;
    for (int base = 0; base < n + 1; base += 1024) {
        int i = base + (int)threadIdx.x;
        int v = (i < n) ? cntcur[i] : 0;
        sdata[threadIdx.x] = v;
        __syncthreads();
        for (int off = 1; off < 1024; off <<= 1) {
            int t = ((int)threadIdx.x >= off) ? sdata[threadIdx.x - off] : 0;
            __syncthreads();
            sdata[threadIdx.x] += t;
            __syncthreads();
        }
        int incl = sdata[threadIdx.x];
        int total = sdata[1023];
        if (i <= n) {
            int excl = running + incl - v;
            start[i] = excl;
            if (i < n) cntcur[i] = excl;
        }
        running += total;
        __syncthreads();
    }
}

__global__ void k_fill_slots(const int* __restrict__ dst, int* __restrict__ cursor,
                             int* __restrict__ eidT, int E) {
    int e = blockIdx.x * blockDim.x + threadIdx.x;
    if (e >= E) return;
    int p = atomicAdd(&cursor[dst[e]], 1);
    eidT[p] = e;
}

// One WAVE per dst row: deterministic order via rank of original edge id.
__global__ __launch_bounds__(256) void k_rank_scatter(
    const int* __restrict__ eidT, const int* __restrict__ start,
    const int* __restrict__ src, const float* __restrict__ w,
    int* __restrict__ col, float* __restrict__ wv, int nRows, int N) {
    const int wid  = (int)((blockIdx.x * blockDim.x + threadIdx.x) >> 6);
    const int lane = (int)(threadIdx.x & 63);
    if (wid >= nRows) return;
    const int s = start[wid], e = start[wid + 1];
    for (int i = s + lane; i < e; i += 64) {
        const int myeid = eidT[i];
        int rank = 0;
        for (int j = s; j < e; ++j)
            rank += (eidT[j] < myeid) ? 1 : 0;
        const int pos = s + rank;
        const int sc  = src[myeid];
        col[pos] = sc * FDIM;        // pre-scaled
        wv[pos]  = w[(size_t)sc * N + wid];
    }
}

// ---- Fused persistent loop ------------------------------------------------
// One cooperative kernel: init, then 8x { pred/err/dd over all N rows,
// grid.sync, grad/update over NI internal rows, grid.sync }.
// th/dd stored bf16 (halves the dominant random-row gather traffic);
// accumulation in fp32.
__global__ __launch_bounds__(256, 4) void k_loop(
    const int* __restrict__ start, const int* __restrict__ col,
    const float* __restrict__ wv, const float* __restrict__ values_in,
    float* __restrict__ vals, __hip_bfloat16* __restrict__ th,
    float* __restrict__ err, __hip_bfloat16* __restrict__ dd,
    int N, int NI)
{
    cg::grid_group grid = cg::this_grid();
    const int f  = (int)threadIdx.x;
    const int nb = (int)gridDim.x;

    __shared__ int   s_col[CHUNK];
    __shared__ float s_w[CHUNK];

    // init: vals = values, th = tanh(values)
    for (int r = blockIdx.x; r < N; r += nb) {
        const int idx = r * FDIM + f;
        const float v = values_in[idx];
        vals[idx] = v;
        th[idx] = __float2bfloat16(tanhf(v));
    }
    grid.sync();

    for (int t = 0; t < T_STEPS; ++t) {
        // Phase A (all rows): pred = sum w_e*th[col]; err; dd = 1 - tanh(err)^2
        for (int d = blockIdx.x; d < N; d += nb) {
            const int s = start[d], e = start[d + 1];
            float acc = 0.f;
            for (int base = s; base < e; base += CHUNK) {
                const int cnt = min(CHUNK, e - base);
                __syncthreads();
                if (f < cnt) { s_col[f] = col[base + f]; s_w[f] = wv[base + f]; }
                __syncthreads();
                #pragma unroll 4
                for (int j = 0; j < cnt; ++j)
                    acc = fmaf(s_w[j], __bfloat162float(th[s_col[j] + f]), acc);
            }
            const int idx = d * FDIM + f;
            const float er = vals[idx] - acc;
            err[idx] = er;
            const float u = tanhf(er);
            dd[idx] = __float2bfloat16(1.f - u * u);
            __syncthreads();
        }
        grid.sync();

        // Phase B (internal rows): g = sum w_e*dd[col]; vals -= lr*(err - g)
        for (int d = blockIdx.x; d < NI; d += nb) {
            const int s = start[d], e = start[d + 1];
            float g = 0.f;
            for (int base = s; base < e; base += CHUNK) {
                const int cnt = min(CHUNK, e - base);
                __syncthreads();
                if (f < cnt) { s_col[f] = col[base + f]; s_w[f] = wv[base + f]; }
                __syncthreads();
                #pragma unroll 4
                for (int j = 0; j < cnt; ++j)
                    g = fmaf(s_w[j], __bfloat162float(dd[s_col[j] + f]), g);
            }
            const int idx = d * FDIM + f;
            const float nv = vals[idx] - LR_X * (err[idx] - g);
            vals[idx] = nv;
            th[idx] = __float2bfloat16(tanhf(nv));
            __syncthreads();
        }
        grid.sync();
    }
}

// ---- Launch ---------------------------------------------------------------

extern "C" void kernel_launch(void* const* d_in, const int* in_sizes, int n_in,
                              void* d_out, int out_size, void* d_ws, size_t ws_size,
                              hipStream_t stream) {
    const float* values = (const float*)d_in[0];
    const float* w      = (const float*)d_in[1];
    const int*   edge   = (const int*)d_in[2];
    const int NF = in_sizes[0];            // N*F
    int N  = NF / FDIM;                    // 5000
    const int E  = in_sizes[2] / 2;        // 160000
    int NI = in_sizes[3];                  // 2500
    const int* srcp = edge;
    const int* dstp = edge + E;
    float* vals = (float*)d_out;           // working values live in d_out

    char* ws = (char*)d_ws;
    size_t off = 0;
    auto alloc = [&](size_t bytes) {
        void* p = ws + off;
        off = (off + bytes + 255) & ~(size_t)255;
        return p;
    };
    int*   start = (int*)  alloc((size_t)(N + 1) * sizeof(int));
    int*   cur   = (int*)  alloc((size_t)N * sizeof(int));
    int*   eidT  = (int*)  alloc((size_t)E * sizeof(int));
    int*   col   = (int*)  alloc((size_t)E * sizeof(int));   // pre-scaled by FDIM
    float* wv    = (float*)alloc((size_t)E * sizeof(float));
    __hip_bfloat16* th = (__hip_bfloat16*)alloc((size_t)NF * sizeof(__hip_bfloat16));
    __hip_bfloat16* dd = (__hip_bfloat16*)alloc((size_t)NF * sizeof(__hip_bfloat16));
    float* err   = (float*)alloc((size_t)NF * sizeof(float));
    (void)ws_size; (void)n_in; (void)out_size;

    hipMemsetAsync(cur, 0, (size_t)N * sizeof(int), stream);
    const int gE = (E + 255) / 256;
    k_count<<<gE, 256, 0, stream>>>(dstp, cur, E);
    k_scan<<<1, 1024, 0, stream>>>(cur, start, N);
    k_fill_slots<<<gE, 256, 0, stream>>>(dstp, cur, eidT, E);
    k_rank_scatter<<<(N + 3) / 4, 256, 0, stream>>>(eidT, start, srcp, w, col, wv, N, N);

    void* args[] = {(void*)&start, (void*)&col, (void*)&wv, (void*)&values,
                    (void*)&vals, (void*)&th, (void*)&err, (void*)&dd,
                    (void*)&N, (void*)&NI};
    hipLaunchCooperativeKernel((const void*)k_loop, dim3(GRID_PERSIST), dim3(FDIM),
                               args, 0, stream);
}

// Round 4
// 304.235 us; speedup vs baseline: 7.7980x; 7.7980x over previous
//
#include <hip/hip_runtime.h>
#include <hip/hip_bf16.h>

#define FDIM 256
#define T_STEPS 8
#define LR_X 0.1f

// ---- CSR build ------------------------------------------------------------

__global__ void k_count(const int* __restrict__ dst, int* __restrict__ cnt, int E) {
    int e = blockIdx.x * blockDim.x + threadIdx.x;
    if (e < E) atomicAdd(&cnt[dst[e]], 1);
}

// Exclusive scan of counts (in cntcur) -> start[0..n] and cursor back into cntcur.
__global__ __launch_bounds__(1024) void k_scan(int* cntcur, int* start, int n) {
    __shared__ int sdata[1024];
    int running = 0;
    for (int base = 0; base < n + 1; base += 1024) {
        int i = base + (int)threadIdx.x;
        int v = (i < n) ? cntcur[i] : 0;
        sdata[threadIdx.x] = v;
        __syncthreads();
        for (int off = 1; off < 1024; off <<= 1) {
            int t = ((int)threadIdx.x >= off) ? sdata[threadIdx.x - off] : 0;
            __syncthreads();
            sdata[threadIdx.x] += t;
            __syncthreads();
        }
        int incl = sdata[threadIdx.x];
        int total = sdata[1023];
        if (i <= n) {
            int excl = running + incl - v;
            start[i] = excl;
            if (i < n) cntcur[i] = excl;
        }
        running += total;
        __syncthreads();
    }
}

__global__ void k_fill_slots(const int* __restrict__ dst, int* __restrict__ cursor,
                             int* __restrict__ eidT, int E) {
    int e = blockIdx.x * blockDim.x + threadIdx.x;
    if (e >= E) return;
    int p = atomicAdd(&cursor[dst[e]], 1);
    eidT[p] = e;
}

// One WAVE per dst row: deterministic order via rank of original edge id.
__global__ __launch_bounds__(256) void k_rank_scatter(
    const int* __restrict__ eidT, const int* __restrict__ start,
    const int* __restrict__ src, const float* __restrict__ w,
    int* __restrict__ col, float* __restrict__ wv, int nRows, int N) {
    const int wid  = (int)((blockIdx.x * blockDim.x + threadIdx.x) >> 6);
    const int lane = (int)(threadIdx.x & 63);
    if (wid >= nRows) return;
    const int s = start[wid], e = start[wid + 1];
    for (int i = s + lane; i < e; i += 64) {
        const int myeid = eidT[i];
        int rank = 0;
        for (int j = s; j < e; ++j)
            rank += (eidT[j] < myeid) ? 1 : 0;
        const int pos = s + rank;
        const int sc  = src[myeid];
        col[pos] = sc * FDIM;        // pre-scaled element offset
        wv[pos]  = w[(size_t)sc * N + wid];
    }
}

// vals (working copy in d_out) = values; th = tanh(values) in bf16
__global__ void k_init(const float* __restrict__ vin, float* __restrict__ vals,
                       __hip_bfloat16* __restrict__ th, int n) {
    int i = blockIdx.x * blockDim.x + threadIdx.x;
    if (i < n) {
        float v = vin[i];
        vals[i] = v;
        th[i] = __float2bfloat16(tanhf(v));
    }
}

// ---- Per-step kernels (barrier-free: shfl-broadcast edge loop) -------------

// One block (4 waves) per dst row d. thread f = feature f (0..255).
// Each wave loads 64 (col,wv) pairs coalesced, then broadcasts via __shfl.
// pred = sum_e w_e * th[col_e][f]; err = vals - pred; dd = 1 - tanh(err)^2
__global__ __launch_bounds__(FDIM) void k_pred_err(
    const int* __restrict__ start, const int* __restrict__ col,
    const float* __restrict__ wv, const float* __restrict__ vals,
    const __hip_bfloat16* __restrict__ th, float* __restrict__ err,
    __hip_bfloat16* __restrict__ dd) {
    const int d = blockIdx.x;
    const int f = (int)threadIdx.x;
    const int lane = f & 63;
    const int s = start[d], e = start[d + 1];
    float a0 = 0.f, a1 = 0.f, a2 = 0.f, a3 = 0.f;
    for (int base = s; base < e; base += 64) {
        const int n = min(64, e - base);
        int   c  = 0;
        float ww = 0.f;
        if (lane < n) { c = col[base + lane]; ww = wv[base + lane]; }
        int j = 0;
        for (; j + 4 <= n; j += 4) {
            const int   c0 = __shfl(c, j),     c1 = __shfl(c, j + 1);
            const int   c2 = __shfl(c, j + 2), c3 = __shfl(c, j + 3);
            const float w0 = __shfl(ww, j),     w1 = __shfl(ww, j + 1);
            const float w2 = __shfl(ww, j + 2), w3 = __shfl(ww, j + 3);
            a0 = fmaf(w0, __bfloat162float(th[c0 + f]), a0);
            a1 = fmaf(w1, __bfloat162float(th[c1 + f]), a1);
            a2 = fmaf(w2, __bfloat162float(th[c2 + f]), a2);
            a3 = fmaf(w3, __bfloat162float(th[c3 + f]), a3);
        }
        for (; j < n; ++j)
            a0 = fmaf(__shfl(ww, j), __bfloat162float(th[__shfl(c, j) + f]), a0);
    }
    const float acc = (a0 + a1) + (a2 + a3);
    const int idx = d * FDIM + f;
    const float er = vals[idx] - acc;
    err[idx] = er;
    const float u = tanhf(er);
    dd[idx] = __float2bfloat16(1.f - u * u);
}

// One block per INTERNAL dst row d (< NI).
// g = sum_e w_e * dd[col_e][f]; vals[d] -= lr*(err[d]-g); th[d] = tanh(vals[d])
__global__ __launch_bounds__(FDIM) void k_grad_update(
    const int* __restrict__ start, const int* __restrict__ col,
    const float* __restrict__ wv, const float* __restrict__ err,
    const __hip_bfloat16* __restrict__ dd, float* __restrict__ vals,
    __hip_bfloat16* __restrict__ th) {
    const int d = blockIdx.x;
    const int f = (int)threadIdx.x;
    const int lane = f & 63;
    const int s = start[d], e = start[d + 1];
    float a0 = 0.f, a1 = 0.f, a2 = 0.f, a3 = 0.f;
    for (int base = s; base < e; base += 64) {
        const int n = min(64, e - base);
        int   c  = 0;
        float ww = 0.f;
        if (lane < n) { c = col[base + lane]; ww = wv[base + lane]; }
        int j = 0;
        for (; j + 4 <= n; j += 4) {
            const int   c0 = __shfl(c, j),     c1 = __shfl(c, j + 1);
            const int   c2 = __shfl(c, j + 2), c3 = __shfl(c, j + 3);
            const float w0 = __shfl(ww, j),     w1 = __shfl(ww, j + 1);
            const float w2 = __shfl(ww, j + 2), w3 = __shfl(ww, j + 3);
            a0 = fmaf(w0, __bfloat162float(dd[c0 + f]), a0);
            a1 = fmaf(w1, __bfloat162float(dd[c1 + f]), a1);
            a2 = fmaf(w2, __bfloat162float(dd[c2 + f]), a2);
            a3 = fmaf(w3, __bfloat162float(dd[c3 + f]), a3);
        }
        for (; j < n; ++j)
            a0 = fmaf(__shfl(ww, j), __bfloat162float(dd[__shfl(c, j) + f]), a0);
    }
    const float g = (a0 + a1) + (a2 + a3);
    const int idx = d * FDIM + f;
    const float nv = vals[idx] - LR_X * (err[idx] - g);
    vals[idx] = nv;
    th[idx] = __float2bfloat16(tanhf(nv));
}

// ---- Launch ---------------------------------------------------------------

extern "C" void kernel_launch(void* const* d_in, const int* in_sizes, int n_in,
                              void* d_out, int out_size, void* d_ws, size_t ws_size,
                              hipStream_t stream) {
    const float* values = (const float*)d_in[0];
    const float* w      = (const float*)d_in[1];
    const int*   edge   = (const int*)d_in[2];
    const int NF = in_sizes[0];            // N*F
    const int N  = NF / FDIM;              // 5000
    const int E  = in_sizes[2] / 2;        // 160000
    const int NI = in_sizes[3];            // 2500
    const int* srcp = edge;
    const int* dstp = edge + E;
    float* vals = (float*)d_out;           // working values live in d_out

    char* ws = (char*)d_ws;
    size_t off = 0;
    auto alloc = [&](size_t bytes) {
        void* p = ws + off;
        off = (off + bytes + 255) & ~(size_t)255;
        return p;
    };
    int*   start = (int*)  alloc((size_t)(N + 1) * sizeof(int));
    int*   cur   = (int*)  alloc((size_t)N * sizeof(int));
    int*   eidT  = (int*)  alloc((size_t)E * sizeof(int));
    int*   col   = (int*)  alloc((size_t)E * sizeof(int));   // pre-scaled by FDIM
    float* wv    = (float*)alloc((size_t)E * sizeof(float));
    __hip_bfloat16* th = (__hip_bfloat16*)alloc((size_t)NF * sizeof(__hip_bfloat16));
    __hip_bfloat16* dd = (__hip_bfloat16*)alloc((size_t)NF * sizeof(__hip_bfloat16));
    float* err   = (float*)alloc((size_t)NF * sizeof(float));
    (void)ws_size; (void)n_in; (void)out_size;

    hipMemsetAsync(cur, 0, (size_t)N * sizeof(int), stream);
    const int gE = (E + 255) / 256;
    k_count<<<gE, 256, 0, stream>>>(dstp, cur, E);
    k_scan<<<1, 1024, 0, stream>>>(cur, start, N);
    k_fill_slots<<<gE, 256, 0, stream>>>(dstp, cur, eidT, E);
    k_rank_scatter<<<(N + 3) / 4, 256, 0, stream>>>(eidT, start, srcp, w, col, wv, N, N);
    k_init<<<(NF + 255) / 256, 256, 0, stream>>>(values, vals, th, NF);

    for (int t = 0; t < T_STEPS; ++t) {
        k_pred_err<<<N, FDIM, 0, stream>>>(start, col, wv, vals, th, err, dd);
        k_grad_update<<<NI, FDIM, 0, stream>>>(start, col, wv, err, dd, vals, th);
    }
}

// Round 5
// 242.407 us; speedup vs baseline: 9.7869x; 1.2551x over previous
//
#include <hip/hip_runtime.h>
#include <hip/hip_bf16.h>

#define FDIM 256
#define CHUNK 64
#define T_STEPS 8
#define LR_X 0.1f
#define EXT_BIT (1 << 24)

__device__ __forceinline__ float ftanh(float x) {
    // tanh(x) = sign(x) * (1 - e^{-2|x|}) / (1 + e^{-2|x|}); hw exp + hw rcp
    float ax = fabsf(x);
    float z  = __expf(-2.f * ax);
    float t  = (1.f - z) * __builtin_amdgcn_rcpf(1.f + z);
    return copysignf(t, x);
}

// ---- CSR build ------------------------------------------------------------

__global__ void k_count(const int* __restrict__ dst, int* __restrict__ cnt, int E) {
    int e = blockIdx.x * blockDim.x + threadIdx.x;
    if (e < E) atomicAdd(&cnt[dst[e]], 1);
}

__global__ __launch_bounds__(1024) void k_scan(int* cntcur, int* start, int n) {
    __shared__ int sdata[1024];
    int running = 0;
    for (int base = 0; base < n + 1; base += 1024) {
        int i = base + (int)threadIdx.x;
        int v = (i < n) ? cntcur[i] : 0;
        sdata[threadIdx.x] = v;
        __syncthreads();
        for (int off = 1; off < 1024; off <<= 1) {
            int t = ((int)threadIdx.x >= off) ? sdata[threadIdx.x - off] : 0;
            __syncthreads();
            sdata[threadIdx.x] += t;
            __syncthreads();
        }
        int incl = sdata[threadIdx.x];
        int total = sdata[1023];
        if (i <= n) {
            int excl = running + incl - v;
            start[i] = excl;
            if (i < n) cntcur[i] = excl;
        }
        running += total;
        __syncthreads();
    }
}

__global__ void k_fill_slots(const int* __restrict__ dst, int* __restrict__ cursor,
                             int* __restrict__ eidT, int E) {
    int e = blockIdx.x * blockDim.x + threadIdx.x;
    if (e >= E) return;
    int p = atomicAdd(&cursor[dst[e]], 1);
    eidT[p] = e;
}

// key = (is_external_col << 24) | eid  -> internal-col edges sort first,
// deterministic within class by original edge id. Also cache src per slot.
__global__ void k_key(const int* __restrict__ eidT, const int* __restrict__ src,
                      int* __restrict__ keyT, int* __restrict__ colS, int E, int NI) {
    int p = blockIdx.x * blockDim.x + threadIdx.x;
    if (p >= E) return;
    int e  = eidT[p];
    int sc = src[e];
    keyT[p] = ((sc >= NI) ? EXT_BIT : 0) | e;
    colS[p] = sc;
}

// One WAVE per dst row: deterministic rank by key; writes col (pre-scaled),
// wv = w[src,dst], and mid[row] = start + (#internal-col edges).
__global__ __launch_bounds__(256) void k_rank_scatter(
    const int* __restrict__ keyT, const int* __restrict__ colS,
    const int* __restrict__ start, const float* __restrict__ w,
    int* __restrict__ col, float* __restrict__ wv, int* __restrict__ mid,
    int nRows, int N) {
    const int wid  = (int)((blockIdx.x * blockDim.x + threadIdx.x) >> 6);
    const int lane = (int)(threadIdx.x & 63);
    if (wid >= nRows) return;
    const int s = start[wid], e = start[wid + 1];
    int nInt = 0;
    for (int i = s + lane; i < e; i += 64) {
        const int myk = keyT[i];
        int rank = 0;
        for (int j = s; j < e; ++j)
            rank += (keyT[j] < myk) ? 1 : 0;
        const int pos = s + rank;
        const int sc  = colS[i];
        col[pos] = sc * FDIM;
        wv[pos]  = w[(size_t)sc * N + wid];
        nInt += (myk < EXT_BIT) ? 1 : 0;
    }
    // wave-reduce nInt
    for (int off = 1; off < 64; off <<= 1)
        nInt += __shfl_xor(nInt, off);
    if (lane == 0) mid[wid] = s + nInt;
}

// vals = values; th = bf16(tanh(values))
__global__ void k_init(const float* __restrict__ vin, float* __restrict__ vals,
                       __hip_bfloat16* __restrict__ th, int n) {
    int i = blockIdx.x * blockDim.x + threadIdx.x;
    if (i < n) {
        float v = vin[i];
        vals[i] = v;
        th[i] = __float2bfloat16(ftanh(v));
    }
}

// Constant external-col contribution, computed once:
// predc[d][f] = sum_{e in [mid,end)} w_e * th[col_e][f]
__global__ __launch_bounds__(FDIM) void k_predc(
    const int* __restrict__ mid, const int* __restrict__ start,
    const int* __restrict__ col, const float* __restrict__ wv,
    const __hip_bfloat16* __restrict__ th, float* __restrict__ predc) {
    const int d = blockIdx.x;
    const int f = (int)threadIdx.x;
    const int m = mid[d], e = start[d + 1];
    __shared__ int   s_col[CHUNK];
    __shared__ float s_w[CHUNK];
    float acc = 0.f;
    for (int base = m; base < e; base += CHUNK) {
        const int cnt = min(CHUNK, e - base);
        __syncthreads();
        if (f < cnt) { s_col[f] = col[base + f]; s_w[f] = wv[base + f]; }
        __syncthreads();
        for (int j = 0; j < cnt; ++j)
            acc = fmaf(s_w[j], __bfloat162float(th[s_col[j] + f]), acc);
    }
    predc[d * FDIM + f] = acc;
}

// ---- Per-step kernels -----------------------------------------------------

// pred = predc + sum_{[s,mid)} w_e*th[col]; err (internal only); dd = 1-tanh(err)^2
__global__ __launch_bounds__(FDIM) void k_pred(
    const int* __restrict__ start, const int* __restrict__ mid,
    const int* __restrict__ col, const float* __restrict__ wv,
    const float* __restrict__ vals, const float* __restrict__ predc,
    const __hip_bfloat16* __restrict__ th, float* __restrict__ err,
    __hip_bfloat16* __restrict__ dd, int NI) {
    const int d = blockIdx.x;
    const int f = (int)threadIdx.x;
    const int s = start[d], m = mid[d];
    __shared__ int   s_col[CHUNK];
    __shared__ float s_w[CHUNK];
    float acc = 0.f;
    for (int base = s; base < m; base += CHUNK) {
        const int cnt = min(CHUNK, m - base);
        __syncthreads();
        if (f < cnt) { s_col[f] = col[base + f]; s_w[f] = wv[base + f]; }
        __syncthreads();
        for (int j = 0; j < cnt; ++j)
            acc = fmaf(s_w[j], __bfloat162float(th[s_col[j] + f]), acc);
    }
    const int idx = d * FDIM + f;
    const float er = vals[idx] - (predc[idx] + acc);
    if (d < NI) err[idx] = er;
    const float u = ftanh(er);
    dd[idx] = __float2bfloat16(1.f - u * u);
}

// internal rows: g = sum_{[s,e)} w_e*dd[col]; vals -= lr*(err-g); th = tanh(vals)
__global__ __launch_bounds__(FDIM) void k_grad(
    const int* __restrict__ start, const int* __restrict__ col,
    const float* __restrict__ wv, const float* __restrict__ err,
    const __hip_bfloat16* __restrict__ dd, float* __restrict__ vals,
    __hip_bfloat16* __restrict__ th) {
    const int d = blockIdx.x;
    const int f = (int)threadIdx.x;
    const int s = start[d], e = start[d + 1];
    __shared__ int   s_col[CHUNK];
    __shared__ float s_w[CHUNK];
    float g = 0.f;
    for (int base = s; base < e; base += CHUNK) {
        const int cnt = min(CHUNK, e - base);
        __syncthreads();
        if (f < cnt) { s_col[f] = col[base + f]; s_w[f] = wv[base + f]; }
        __syncthreads();
        for (int j = 0; j < cnt; ++j)
            g = fmaf(s_w[j], __bfloat162float(dd[s_col[j] + f]), g);
    }
    const int idx = d * FDIM + f;
    const float nv = vals[idx] - LR_X * (err[idx] - g);
    vals[idx] = nv;
    th[idx] = __float2bfloat16(ftanh(nv));
}

// ---- Launch ---------------------------------------------------------------

extern "C" void kernel_launch(void* const* d_in, const int* in_sizes, int n_in,
                              void* d_out, int out_size, void* d_ws, size_t ws_size,
                              hipStream_t stream) {
    const float* values = (const float*)d_in[0];
    const float* w      = (const float*)d_in[1];
    const int*   edge   = (const int*)d_in[2];
    const int NF = in_sizes[0];            // N*F
    const int N  = NF / FDIM;              // 5000
    const int E  = in_sizes[2] / 2;        // 160000
    const int NI = in_sizes[3];            // 2500
    const int* srcp = edge;
    const int* dstp = edge + E;
    float* vals = (float*)d_out;

    char* ws = (char*)d_ws;
    size_t off = 0;
    auto alloc = [&](size_t bytes) {
        void* p = ws + off;
        off = (off + bytes + 255) & ~(size_t)255;
        return p;
    };
    int*   start = (int*)  alloc((size_t)(N + 1) * sizeof(int));
    int*   cur   = (int*)  alloc((size_t)N * sizeof(int));
    int*   mid   = (int*)  alloc((size_t)N * sizeof(int));
    int*   eidT  = (int*)  alloc((size_t)E * sizeof(int));
    int*   keyT  = (int*)  alloc((size_t)E * sizeof(int));
    int*   colS  = (int*)  alloc((size_t)E * sizeof(int));
    int*   col   = (int*)  alloc((size_t)E * sizeof(int));   // pre-scaled by FDIM
    float* wv    = (float*)alloc((size_t)E * sizeof(float));
    __hip_bfloat16* th = (__hip_bfloat16*)alloc((size_t)NF * sizeof(__hip_bfloat16));
    __hip_bfloat16* dd = (__hip_bfloat16*)alloc((size_t)NF * sizeof(__hip_bfloat16));
    float* err   = (float*)alloc((size_t)NF * sizeof(float));
    float* predc = (float*)alloc((size_t)NF * sizeof(float));
    (void)ws_size; (void)n_in; (void)out_size;

    hipMemsetAsync(cur, 0, (size_t)N * sizeof(int), stream);
    const int gE = (E + 255) / 256;
    k_count<<<gE, 256, 0, stream>>>(dstp, cur, E);
    k_scan<<<1, 1024, 0, stream>>>(cur, start, N);
    k_fill_slots<<<gE, 256, 0, stream>>>(dstp, cur, eidT, E);
    k_key<<<gE, 256, 0, stream>>>(eidT, srcp, keyT, colS, E, NI);
    k_rank_scatter<<<(N + 3) / 4, 256, 0, stream>>>(keyT, colS, start, w, col, wv, mid, N, N);
    k_init<<<(NF + 255) / 256, 256, 0, stream>>>(values, vals, th, NF);
    k_predc<<<N, FDIM, 0, stream>>>(mid, start, col, wv, th, predc);

    for (int t = 0; t < T_STEPS; ++t) {
        k_pred<<<N, FDIM, 0, stream>>>(start, mid, col, wv, vals, predc, th, err, dd, NI);
        k_grad<<<NI, FDIM, 0, stream>>>(start, col, wv, err, dd, vals, th);
    }
}

// Round 6
// 241.307 us; speedup vs baseline: 9.8315x; 1.0046x over previous
//
#include <hip/hip_runtime.h>
#include <hip/hip_bf16.h>

#define FDIM 256
#define F2   128           // bf162 / float2 elements per row
#define T_STEPS 8
#define LR_X 0.1f
#define EXT_BIT (1 << 24)

typedef __hip_bfloat162 bf2;

__device__ __forceinline__ float ftanh(float x) {
    // tanh(x) = sign(x) * (1 - e^{-2|x|}) / (1 + e^{-2|x|}); hw exp + hw rcp
    float ax = fabsf(x);
    float z  = __expf(-2.f * ax);
    float t  = (1.f - z) * __builtin_amdgcn_rcpf(1.f + z);
    return copysignf(t, x);
}
__device__ __forceinline__ float2 bf22f(const bf2 v) {
    return make_float2(__bfloat162float(v.x), __bfloat162float(v.y));
}
__device__ __forceinline__ bf2 f22bf(float x, float y) {
    bf2 r; r.x = __float2bfloat16(x); r.y = __float2bfloat16(y); return r;
}

// ---- CSR build ------------------------------------------------------------

// Fused: blocks [0,gE) count dst degrees; blocks [gE,..) init vals/th (bf162).
__global__ void k_count_init(const int* __restrict__ dst, int* __restrict__ cnt, int E,
                             const float* __restrict__ vin, float* __restrict__ vals,
                             bf2* __restrict__ th2, int NF2, int gE) {
    const int b = (int)blockIdx.x;
    if (b < gE) {
        int e = b * 256 + (int)threadIdx.x;
        if (e < E) atomicAdd(&cnt[dst[e]], 1);
    } else {
        int i = (b - gE) * 256 + (int)threadIdx.x;
        if (i < NF2) {
            float2 v = ((const float2*)vin)[i];
            ((float2*)vals)[i] = v;
            th2[i] = f22bf(ftanh(v.x), ftanh(v.y));
        }
    }
}

__global__ __launch_bounds__(1024) void k_scan(int* cntcur, int* start, int n) {
    __shared__ int sdata[1024];
    int running = 0;
    for (int base = 0; base < n + 1; base += 1024) {
        int i = base + (int)threadIdx.x;
        int v = (i < n) ? cntcur[i] : 0;
        sdata[threadIdx.x] = v;
        __syncthreads();
        for (int off = 1; off < 1024; off <<= 1) {
            int t = ((int)threadIdx.x >= off) ? sdata[threadIdx.x - off] : 0;
            __syncthreads();
            sdata[threadIdx.x] += t;
            __syncthreads();
        }
        int incl = sdata[threadIdx.x];
        int total = sdata[1023];
        if (i <= n) {
            int excl = running + incl - v;
            start[i] = excl;
            if (i < n) cntcur[i] = excl;
        }
        running += total;
        __syncthreads();
    }
}

// Fused fill+key: scatter (key,src) to CSR slot (order fixed by rank below).
__global__ void k_fill(const int* __restrict__ src, const int* __restrict__ dst,
                       int* __restrict__ cursor, int* __restrict__ keyT,
                       int* __restrict__ colS, int E, int NI) {
    int e = blockIdx.x * blockDim.x + threadIdx.x;
    if (e >= E) return;
    int sc = src[e];
    int p = atomicAdd(&cursor[dst[e]], 1);
    keyT[p] = ((sc >= NI) ? EXT_BIT : 0) | e;
    colS[p] = sc;
}

// One WAVE per dst row: deterministic rank by key = (is_ext<<24)|eid.
// col pre-scaled for bf162 indexing (src * F2). mid = start + #internal-col.
__global__ __launch_bounds__(256) void k_rank_scatter(
    const int* __restrict__ keyT, const int* __restrict__ colS,
    const int* __restrict__ start, const float* __restrict__ w,
    int* __restrict__ col, float* __restrict__ wv, int* __restrict__ mid,
    int nRows, int N) {
    const int wid  = (int)((blockIdx.x * blockDim.x + threadIdx.x) >> 6);
    const int lane = (int)(threadIdx.x & 63);
    if (wid >= nRows) return;
    const int s = start[wid], e = start[wid + 1];
    int nInt = 0;
    for (int i = s + lane; i < e; i += 64) {
        const int myk = keyT[i];
        int rank = 0;
        for (int j = s; j < e; ++j)
            rank += (keyT[j] < myk) ? 1 : 0;
        const int pos = s + rank;
        const int sc  = colS[i];
        col[pos] = sc * F2;
        wv[pos]  = w[(size_t)sc * N + wid];
        nInt += (myk < EXT_BIT) ? 1 : 0;
    }
    for (int off = 1; off < 64; off <<= 1)
        nInt += __shfl_xor(nInt, off);
    if (lane == 0) mid[wid] = s + nInt;
}

// ---- Loop kernels: 128 threads/row, 2 features/thread, shfl broadcast ------

__device__ __forceinline__ void gather_acc(
    const int* __restrict__ col, const float* __restrict__ wv,
    const bf2* __restrict__ src2, int s, int e, int lane, int f,
    float& ax, float& ay, float& bx, float& by) {
    for (int base = s; base < e; base += 64) {
        const int n = min(64, e - base);
        int c = 0; float ww = 0.f;
        if (lane < n) { c = col[base + lane]; ww = wv[base + lane]; }
        int j = 0;
        for (; j + 2 <= n; j += 2) {
            const int   c0 = __shfl(c, j),  c1 = __shfl(c, j + 1);
            const float w0 = __shfl(ww, j), w1 = __shfl(ww, j + 1);
            const float2 t0 = bf22f(src2[c0 + f]);
            const float2 t1 = bf22f(src2[c1 + f]);
            ax = fmaf(w0, t0.x, ax); ay = fmaf(w0, t0.y, ay);
            bx = fmaf(w1, t1.x, bx); by = fmaf(w1, t1.y, by);
        }
        for (; j < n; ++j) {
            const int c0 = __shfl(c, j); const float w0 = __shfl(ww, j);
            const float2 t0 = bf22f(src2[c0 + f]);
            ax = fmaf(w0, t0.x, ax); ay = fmaf(w0, t0.y, ay);
        }
    }
}

// Step 0: gather full row; store external-col part to predc (reused 7 steps).
__global__ __launch_bounds__(F2) void k_pred_first(
    const int* __restrict__ start, const int* __restrict__ mid,
    const int* __restrict__ col, const float* __restrict__ wv,
    const float2* __restrict__ vals2, float2* __restrict__ predc2,
    const bf2* __restrict__ th2, float2* __restrict__ err2,
    bf2* __restrict__ dd2, int NI) {
    const int d = (int)blockIdx.x;
    const int f = (int)threadIdx.x;
    const int lane = f & 63;
    const int s = start[d], m = mid[d], e = start[d + 1];
    float ix = 0.f, iy = 0.f, jx = 0.f, jy = 0.f;   // internal part
    float xx = 0.f, xy = 0.f, yx = 0.f, yy = 0.f;   // external part
    gather_acc(col, wv, th2, s, m, lane, f, ix, iy, jx, jy);
    gather_acc(col, wv, th2, m, e, lane, f, xx, xy, yx, yy);
    const int idx = d * F2 + f;
    const float pcx = xx + yx, pcy = xy + yy;
    predc2[idx] = make_float2(pcx, pcy);
    const float2 v = vals2[idx];
    const float ex = v.x - (pcx + ix + jx);
    const float ey = v.y - (pcy + iy + jy);
    if (d < NI) err2[idx] = make_float2(ex, ey);
    const float ux = ftanh(ex), uy = ftanh(ey);
    dd2[idx] = f22bf(1.f - ux * ux, 1.f - uy * uy);
}

// Steps 1..7: internal-col gather + cached predc.
__global__ __launch_bounds__(F2) void k_pred(
    const int* __restrict__ start, const int* __restrict__ mid,
    const int* __restrict__ col, const float* __restrict__ wv,
    const float2* __restrict__ vals2, const float2* __restrict__ predc2,
    const bf2* __restrict__ th2, float2* __restrict__ err2,
    bf2* __restrict__ dd2, int NI) {
    const int d = (int)blockIdx.x;
    const int f = (int)threadIdx.x;
    const int lane = f & 63;
    const int s = start[d], m = mid[d];
    float ax = 0.f, ay = 0.f, bx = 0.f, by = 0.f;
    gather_acc(col, wv, th2, s, m, lane, f, ax, ay, bx, by);
    const int idx = d * F2 + f;
    const float2 pc = predc2[idx];
    const float2 v  = vals2[idx];
    const float ex = v.x - (pc.x + ax + bx);
    const float ey = v.y - (pc.y + ay + by);
    if (d < NI) err2[idx] = make_float2(ex, ey);
    const float ux = ftanh(ex), uy = ftanh(ey);
    dd2[idx] = f22bf(1.f - ux * ux, 1.f - uy * uy);
}

// Internal rows: g = sum w_e*dd[col]; vals -= lr*(err-g); th = tanh(vals).
__global__ __launch_bounds__(F2) void k_grad(
    const int* __restrict__ start, const int* __restrict__ col,
    const float* __restrict__ wv, const float2* __restrict__ err2,
    const bf2* __restrict__ dd2, float2* __restrict__ vals2,
    bf2* __restrict__ th2) {
    const int d = (int)blockIdx.x;
    const int f = (int)threadIdx.x;
    const int lane = f & 63;
    const int s = start[d], e = start[d + 1];
    float ax = 0.f, ay = 0.f, bx = 0.f, by = 0.f;
    gather_acc(col, wv, dd2, s, e, lane, f, ax, ay, bx, by);
    const int idx = d * F2 + f;
    const float2 er = err2[idx];
    const float2 v  = vals2[idx];
    const float nx = v.x - LR_X * (er.x - (ax + bx));
    const float ny = v.y - LR_X * (er.y - (ay + by));
    vals2[idx] = make_float2(nx, ny);
    th2[idx] = f22bf(ftanh(nx), ftanh(ny));
}

// ---- Launch ---------------------------------------------------------------

extern "C" void kernel_launch(void* const* d_in, const int* in_sizes, int n_in,
                              void* d_out, int out_size, void* d_ws, size_t ws_size,
                              hipStream_t stream) {
    const float* values = (const float*)d_in[0];
    const float* w      = (const float*)d_in[1];
    const int*   edge   = (const int*)d_in[2];
    const int NF = in_sizes[0];            // N*F
    const int N  = NF / FDIM;              // 5000
    const int E  = in_sizes[2] / 2;        // 160000
    const int NI = in_sizes[3];            // 2500
    const int NF2 = NF / 2;
    const int* srcp = edge;
    const int* dstp = edge + E;
    float* vals = (float*)d_out;

    char* ws = (char*)d_ws;
    size_t off = 0;
    auto alloc = [&](size_t bytes) {
        void* p = ws + off;
        off = (off + bytes + 255) & ~(size_t)255;
        return p;
    };
    int*   start = (int*)  alloc((size_t)(N + 1) * sizeof(int));
    int*   cur   = (int*)  alloc((size_t)N * sizeof(int));
    int*   mid   = (int*)  alloc((size_t)N * sizeof(int));
    int*   keyT  = (int*)  alloc((size_t)E * sizeof(int));
    int*   colS  = (int*)  alloc((size_t)E * sizeof(int));
    int*   col   = (int*)  alloc((size_t)E * sizeof(int));   // pre-scaled by F2
    float* wv    = (float*)alloc((size_t)E * sizeof(float));
    bf2*   th2   = (bf2*)  alloc((size_t)NF2 * sizeof(bf2));
    bf2*   dd2   = (bf2*)  alloc((size_t)NF2 * sizeof(bf2));
    float* err   = (float*)alloc((size_t)NF * sizeof(float));
    float* predc = (float*)alloc((size_t)NF * sizeof(float));
    (void)ws_size; (void)n_in; (void)out_size;

    float2* vals2  = (float2*)vals;
    float2* err2   = (float2*)err;
    float2* predc2 = (float2*)predc;

    hipMemsetAsync(cur, 0, (size_t)N * sizeof(int), stream);
    const int gE   = (E + 255) / 256;
    const int gNF2 = (NF2 + 255) / 256;
    k_count_init<<<gE + gNF2, 256, 0, stream>>>(dstp, cur, E, values, vals, th2, NF2, gE);
    k_scan<<<1, 1024, 0, stream>>>(cur, start, N);
    k_fill<<<gE, 256, 0, stream>>>(srcp, dstp, cur, keyT, colS, E, NI);
    k_rank_scatter<<<(N + 3) / 4, 256, 0, stream>>>(keyT, colS, start, w, col, wv, mid, N, N);

    for (int t = 0; t < T_STEPS; ++t) {
        if (t == 0)
            k_pred_first<<<N, F2, 0, stream>>>(start, mid, col, wv, vals2, predc2, th2, err2, dd2, NI);
        else
            k_pred<<<N, F2, 0, stream>>>(start, mid, col, wv, vals2, predc2, th2, err2, dd2, NI);
        k_grad<<<NI, F2, 0, stream>>>(start, col, wv, err2, dd2, vals2, th2);
    }
}

// Round 7
// 221.507 us; speedup vs baseline: 10.7103x; 1.0894x over previous
//
#include <hip/hip_runtime.h>
#include <hip/hip_bf16.h>

#define FDIM 256
#define F2   128           // bf162 / float2 elements per row
#define CAP  256           // padded CSR row capacity (max degree << CAP for Poisson(32))
#define T_STEPS 8
#define LR_X 0.1f
#define EXT_BIT (1 << 24)

typedef __hip_bfloat162 bf2;

__device__ __forceinline__ float ftanh(float x) {
    // tanh(x) = sign(x) * (1 - e^{-2|x|}) / (1 + e^{-2|x|}); hw exp + hw rcp
    float ax = fabsf(x);
    float z  = __expf(-2.f * ax);
    float t  = (1.f - z) * __builtin_amdgcn_rcpf(1.f + z);
    return copysignf(t, x);
}
__device__ __forceinline__ float2 bf22f(const bf2 v) {
    return make_float2(__bfloat162float(v.x), __bfloat162float(v.y));
}
__device__ __forceinline__ bf2 f22bf(float x, float y) {
    bf2 r; r.x = __float2bfloat16(x); r.y = __float2bfloat16(y); return r;
}

// ---- Build (padded CSR: no scan needed) -----------------------------------

// Fused: blocks [0,gE) scatter edges into padded rows (atomic slot, order fixed
// later by rank); blocks [gE,..) init vals/th2.
__global__ void k_fill_init(const int* __restrict__ src, const int* __restrict__ dst,
                            int* __restrict__ cnt, int* __restrict__ keyT,
                            int* __restrict__ colS, int E, int NI,
                            const float* __restrict__ vin, float* __restrict__ vals,
                            bf2* __restrict__ th2, int NF2, int gE) {
    const int b = (int)blockIdx.x;
    if (b < gE) {
        int e = b * 256 + (int)threadIdx.x;
        if (e < E) {
            int sc = src[e];
            int d  = dst[e];
            int p  = atomicAdd(&cnt[d], 1);       // cnt ends as degree
            keyT[d * CAP + p] = ((sc >= NI) ? EXT_BIT : 0) | e;
            colS[d * CAP + p] = sc;
        }
    } else {
        int i = (b - gE) * 256 + (int)threadIdx.x;
        if (i < NF2) {
            float2 v = ((const float2*)vin)[i];
            ((float2*)vals)[i] = v;
            th2[i] = f22bf(ftanh(v.x), ftanh(v.y));
        }
    }
}

// One WAVE per row: deterministic order via rank of key = (is_ext<<24)|eid
// (eids unique -> total order). Writes fused (col*F2, w-bits) pairs; internal
// columns first. nint[row] = #internal-col edges. Gathers w[src,dst] here.
__global__ __launch_bounds__(256) void k_rank_scatter(
    const int* __restrict__ keyT, const int* __restrict__ colS,
    const int* __restrict__ cnt, const float* __restrict__ w,
    int2* __restrict__ cw, int* __restrict__ nint, int nRows, int N) {
    const int wid  = (int)((blockIdx.x * blockDim.x + threadIdx.x) >> 6);
    const int lane = (int)(threadIdx.x & 63);
    if (wid >= nRows) return;
    const int base = wid * CAP;
    const int deg  = cnt[wid];
    int nInt = 0;
    for (int i = lane; i < deg; i += 64) {
        const int myk = keyT[base + i];
        int rank = 0;
        for (int j = 0; j < deg; ++j)
            rank += (keyT[base + j] < myk) ? 1 : 0;
        const int sc = colS[base + i];
        int2 p;
        p.x = sc * F2;
        p.y = __float_as_int(w[(size_t)sc * N + wid]);
        cw[base + rank] = p;
        nInt += (myk < EXT_BIT) ? 1 : 0;
    }
    for (int off = 1; off < 64; off <<= 1)
        nInt += __shfl_xor(nInt, off);
    if (lane == 0) nint[wid] = nInt;
}

// ---- Loop kernels: 2 rows/block, 128 threads/row, shfl broadcast -----------

__device__ __forceinline__ void gather_acc(
    const int2* __restrict__ cw, const bf2* __restrict__ src2,
    int s, int e, int lane, int f,
    float& ax, float& ay, float& bx, float& by) {
    for (int base = s; base < e; base += 64) {
        const int n = min(64, e - base);
        int c = 0; float ww = 0.f;
        if (lane < n) { int2 p = cw[base + lane]; c = p.x; ww = __int_as_float(p.y); }
        int j = 0;
        for (; j + 2 <= n; j += 2) {
            const int   c0 = __shfl(c, j),  c1 = __shfl(c, j + 1);
            const float w0 = __shfl(ww, j), w1 = __shfl(ww, j + 1);
            const float2 t0 = bf22f(src2[c0 + f]);
            const float2 t1 = bf22f(src2[c1 + f]);
            ax = fmaf(w0, t0.x, ax); ay = fmaf(w0, t0.y, ay);
            bx = fmaf(w1, t1.x, bx); by = fmaf(w1, t1.y, by);
        }
        for (; j < n; ++j) {
            const int c0 = __shfl(c, j); const float w0 = __shfl(ww, j);
            const float2 t0 = bf22f(src2[c0 + f]);
            ax = fmaf(w0, t0.x, ax); ay = fmaf(w0, t0.y, ay);
        }
    }
}

// Step 0: full-row gather; stores external-col part to predc (reused 7 steps).
__global__ __launch_bounds__(256) void k_pred_first(
    const int* __restrict__ nint, const int* __restrict__ cnt,
    const int2* __restrict__ cw, const float2* __restrict__ vals2,
    float2* __restrict__ predc2, const bf2* __restrict__ th2,
    float2* __restrict__ err2, bf2* __restrict__ dd2, int N, int NI) {
    const int r = (int)blockIdx.x * 2 + ((int)threadIdx.x >> 7);
    if (r >= N) return;
    const int f = (int)threadIdx.x & 127;
    const int lane = (int)threadIdx.x & 63;
    const int base = r * CAP;
    const int m = base + nint[r], e = base + cnt[r];
    float ix = 0.f, iy = 0.f, jx = 0.f, jy = 0.f;   // internal-col part
    float xx = 0.f, xy = 0.f, yx = 0.f, yy = 0.f;   // external-col part
    gather_acc(cw, th2, base, m, lane, f, ix, iy, jx, jy);
    gather_acc(cw, th2, m, e, lane, f, xx, xy, yx, yy);
    const int idx = r * F2 + f;
    const float pcx = xx + yx, pcy = xy + yy;
    predc2[idx] = make_float2(pcx, pcy);
    const float2 v = vals2[idx];
    const float ex = v.x - (pcx + ix + jx);
    const float ey = v.y - (pcy + iy + jy);
    if (r < NI) err2[idx] = make_float2(ex, ey);
    const float ux = ftanh(ex), uy = ftanh(ey);
    dd2[idx] = f22bf(1.f - ux * ux, 1.f - uy * uy);
}

// Steps 1..7: internal-col gather + cached predc.
__global__ __launch_bounds__(256) void k_pred(
    const int* __restrict__ nint, const int2* __restrict__ cw,
    const float2* __restrict__ vals2, const float2* __restrict__ predc2,
    const bf2* __restrict__ th2, float2* __restrict__ err2,
    bf2* __restrict__ dd2, int N, int NI) {
    const int r = (int)blockIdx.x * 2 + ((int)threadIdx.x >> 7);
    if (r >= N) return;
    const int f = (int)threadIdx.x & 127;
    const int lane = (int)threadIdx.x & 63;
    const int base = r * CAP;
    const int m = base + nint[r];
    float ax = 0.f, ay = 0.f, bx = 0.f, by = 0.f;
    gather_acc(cw, th2, base, m, lane, f, ax, ay, bx, by);
    const int idx = r * F2 + f;
    const float2 pc = predc2[idx];
    const float2 v  = vals2[idx];
    const float ex = v.x - (pc.x + ax + bx);
    const float ey = v.y - (pc.y + ay + by);
    if (r < NI) err2[idx] = make_float2(ex, ey);
    const float ux = ftanh(ex), uy = ftanh(ey);
    dd2[idx] = f22bf(1.f - ux * ux, 1.f - uy * uy);
}

// Internal rows: g = sum w_e*dd[col]; vals -= lr*(err-g); th = tanh(vals).
__global__ __launch_bounds__(256) void k_grad(
    const int* __restrict__ cnt, const int2* __restrict__ cw,
    const float2* __restrict__ err2, const bf2* __restrict__ dd2,
    float2* __restrict__ vals2, bf2* __restrict__ th2, int NI) {
    const int r = (int)blockIdx.x * 2 + ((int)threadIdx.x >> 7);
    if (r >= NI) return;
    const int f = (int)threadIdx.x & 127;
    const int lane = (int)threadIdx.x & 63;
    const int base = r * CAP;
    const int e = base + cnt[r];
    float ax = 0.f, ay = 0.f, bx = 0.f, by = 0.f;
    gather_acc(cw, dd2, base, e, lane, f, ax, ay, bx, by);
    const int idx = r * F2 + f;
    const float2 er = err2[idx];
    const float2 v  = vals2[idx];
    const float nx = v.x - LR_X * (er.x - (ax + bx));
    const float ny = v.y - LR_X * (er.y - (ay + by));
    vals2[idx] = make_float2(nx, ny);
    th2[idx] = f22bf(ftanh(nx), ftanh(ny));
}

// ---- Launch ---------------------------------------------------------------

extern "C" void kernel_launch(void* const* d_in, const int* in_sizes, int n_in,
                              void* d_out, int out_size, void* d_ws, size_t ws_size,
                              hipStream_t stream) {
    const float* values = (const float*)d_in[0];
    const float* w      = (const float*)d_in[1];
    const int*   edge   = (const int*)d_in[2];
    const int NF = in_sizes[0];            // N*F
    const int N  = NF / FDIM;              // 5000
    const int E  = in_sizes[2] / 2;        // 160000
    const int NI = in_sizes[3];            // 2500
    const int NF2 = NF / 2;
    const int* srcp = edge;
    const int* dstp = edge + E;
    float* vals = (float*)d_out;

    char* ws = (char*)d_ws;
    size_t off = 0;
    auto alloc = [&](size_t bytes) {
        void* p = ws + off;
        off = (off + bytes + 255) & ~(size_t)255;
        return p;
    };
    int*  cnt  = (int*) alloc((size_t)N * sizeof(int));
    int*  nint = (int*) alloc((size_t)N * sizeof(int));
    int*  keyT = (int*) alloc((size_t)N * CAP * sizeof(int));
    int*  colS = (int*) alloc((size_t)N * CAP * sizeof(int));
    int2* cw   = (int2*)alloc((size_t)N * CAP * sizeof(int2));
    bf2*  th2  = (bf2*) alloc((size_t)NF2 * sizeof(bf2));
    bf2*  dd2  = (bf2*) alloc((size_t)NF2 * sizeof(bf2));
    float* err   = (float*)alloc((size_t)NF * sizeof(float));
    float* predc = (float*)alloc((size_t)NF * sizeof(float));
    (void)ws_size; (void)n_in; (void)out_size;

    float2* vals2  = (float2*)vals;
    float2* err2   = (float2*)err;
    float2* predc2 = (float2*)predc;

    hipMemsetAsync(cnt, 0, (size_t)N * sizeof(int), stream);
    const int gE   = (E + 255) / 256;
    const int gNF2 = (NF2 + 255) / 256;
    k_fill_init<<<gE + gNF2, 256, 0, stream>>>(srcp, dstp, cnt, keyT, colS, E, NI,
                                               values, vals, th2, NF2, gE);
    k_rank_scatter<<<(N + 3) / 4, 256, 0, stream>>>(keyT, colS, cnt, w, cw, nint, N, N);

    const int gP = (N + 1) / 2;
    const int gG = (NI + 1) / 2;
    for (int t = 0; t < T_STEPS; ++t) {
        if (t == 0)
            k_pred_first<<<gP, 256, 0, stream>>>(nint, cnt, cw, vals2, predc2, th2, err2, dd2, N, NI);
        else
            k_pred<<<gP, 256, 0, stream>>>(nint, cw, vals2, predc2, th2, err2, dd2, N, NI);
        k_grad<<<gG, 256, 0, stream>>>(cnt, cw, err2, dd2, vals2, th2, NI);
    }
}